// Round 6
// baseline (268.674 us; speedup 1.0000x reference)
//
#include <hip/hip_runtime.h>

#define NN 2048
#define NE 8192
#define ED 10
#define EH 32
#define HID 160
#define KT 5440   // 32*160 (w2⊗T) + 160 (root⊗x) + 160 (b2⊗sumx)

typedef __attribute__((ext_vector_type(8))) short short8;
typedef __attribute__((ext_vector_type(4))) float f32x4;
typedef __attribute__((ext_vector_type(4))) ushort us4;
typedef unsigned int u32;

__device__ __forceinline__ ushort f2bf(float v) {   // RNE
    u32 u = __float_as_uint(v);
    u += 0x7FFF + ((u >> 16) & 1);
    return (ushort)(u >> 16);
}

__device__ __forceinline__ short8 mfma_bf16(short8 a, short8 b, f32x4 c);
#define MFMA(a, b, c) __builtin_amdgcn_mfma_f32_16x16x32_bf16(a, b, c, 0, 0, 0)

// ---- edge MLP: h = relu(ea @ w1 + b1), both param sets ----
__global__ void k_h2(const float* __restrict__ ea,
                     const float* __restrict__ w1a, const float* __restrict__ b1a,
                     const float* __restrict__ w1b, const float* __restrict__ b1b,
                     float* __restrict__ ha, float* __restrict__ hb) {
    int idx = blockIdx.x * 256 + threadIdx.x;
    const float* w1 = blockIdx.y ? w1b : w1a;
    const float* b1 = blockIdx.y ? b1b : b1a;
    float* h = blockIdx.y ? hb : ha;
    int e = idx >> 5, j = idx & 31;
    float acc = b1[j];
#pragma unroll
    for (int i = 0; i < ED; ++i) acc += ea[e * ED + i] * w1[i * EH + j];
    h[idx] = fmaxf(acc, 0.f);
}

// ---- Wt[o][k] bf16, k-major rows (B-operand layout), no permutation of w2's
// inner index needed: k = q*160+i maps to w2[q][i*160+o]; then root; then b2.
// 170 panels x 2 sets; blockDim=160 (thread = o)
__global__ __launch_bounds__(160) void k_prepW(
        const float* __restrict__ w2a, const float* __restrict__ b2a,
        const float* __restrict__ roota,
        const float* __restrict__ w2b, const float* __restrict__ b2b,
        const float* __restrict__ rootb,
        ushort* __restrict__ WtA, ushort* __restrict__ WtB) {
    __shared__ float tile[32][161];
    int pb = blockIdx.x, o = threadIdx.x;
    const float* w2 = blockIdx.y ? w2b : w2a;
    const float* b2 = blockIdx.y ? b2b : b2a;
    const float* root = blockIdx.y ? rootb : roota;
    ushort* Wt = blockIdx.y ? WtB : WtA;
    const float* src;
    int kbase;
    if (pb < 160) {                 // w2 panels: q = pb/5, i-panel = pb%5
        int q = pb / 5, ip = pb - q * 5;
        kbase = q * 160 + ip * 32;
        src = w2 + q * (HID * HID) + (ip * 32) * HID;
    } else if (pb < 165) {          // root panels
        int ip = pb - 160;
        kbase = 5120 + ip * 32;
        src = root + (ip * 32) * HID;
    } else {                        // b2 panels
        int ip = pb - 165;
        kbase = 5280 + ip * 32;
        src = b2 + (ip * 32) * HID;
    }
#pragma unroll
    for (int i = 0; i < 32; ++i) tile[i][o] = src[i * HID + o];
    __syncthreads();
    ushort tmp[32];
#pragma unroll
    for (int i = 0; i < 32; ++i) tmp[i] = f2bf(tile[i][o]);
#pragma unroll
    for (int c = 0; c < 8; ++c)
        *(us4*)&Wt[(size_t)o * KT + kbase + c * 4] = *(const us4*)&tmp[c * 4];
}

// ---- dst-CSR: deg, offsets, edge list grouped by dst (single block) ----
__global__ __launch_bounds__(1024) void k_csr(const int* __restrict__ ei,
                                              int* __restrict__ doff,
                                              int* __restrict__ degg,
                                              int* __restrict__ delist) {
    __shared__ int deg[NN], cur[NN], part[1024];
    int t = threadIdx.x;
    deg[t] = 0; deg[t + 1024] = 0;
    __syncthreads();
    for (int e = t; e < NE; e += 1024) atomicAdd(&deg[ei[NE + e]], 1);
    __syncthreads();
    int a0 = deg[2 * t], a1 = deg[2 * t + 1];
    part[t] = a0 + a1;
    __syncthreads();
    for (int st = 1; st < 1024; st <<= 1) {
        int v = (t >= st) ? part[t - st] : 0;
        __syncthreads();
        part[t] += v;
        __syncthreads();
    }
    int base = part[t] - (a0 + a1);
    doff[2 * t] = base;          cur[2 * t] = base;
    doff[2 * t + 1] = base + a0; cur[2 * t + 1] = base + a0;
    degg[2 * t] = a0;            degg[2 * t + 1] = a1;
    __syncthreads();
    for (int e = t; e < NE; e += 1024) {
        int d = ei[NE + e];
        int p = atomicAdd(&cur[d], 1);
        delist[p] = e;
    }
}

// ---- build T[d][0:5440] bf16: msg coeffs (scaled 1/deg), x[d], sumx/deg ----
// one block per dst, blockDim=160 (thread = i); T accumulated in 32 registers
__global__ __launch_bounds__(160) void k_build(
        const float* __restrict__ x, const float* __restrict__ h,
        const int* __restrict__ ei, const int* __restrict__ doff,
        const int* __restrict__ degg, const int* __restrict__ delist,
        ushort* __restrict__ Th, float* __restrict__ oacc) {
    __shared__ float hbuf[64 * EH];
    __shared__ int sbuf[64];
    int d = blockIdx.x, t = threadIdx.x;
    int o0 = doff[d], deg = degg[d];
    float T[32];
#pragma unroll
    for (int q = 0; q < 32; ++q) T[q] = 0.f;
    float sumx = 0.f;
    for (int c0 = 0; c0 < deg; c0 += 64) {
        int nc = min(64, deg - c0);
        for (int j = t; j < nc; j += 160) sbuf[j] = ei[delist[o0 + c0 + j]];
        for (int idx = t; idx < nc * EH; idx += 160) {
            int jj = idx >> 5, qq = idx & 31;
            hbuf[idx] = h[delist[o0 + c0 + jj] * EH + qq];
        }
        __syncthreads();
        for (int j = 0; j < nc; ++j) {
            float xv = x[sbuf[j] * HID + t];
            sumx += xv;
            const float* hj = &hbuf[j * EH];
#pragma unroll
            for (int q = 0; q < 32; ++q) T[q] += hj[q] * xv;
        }
        __syncthreads();
    }
    float dinv = 1.0f / fmaxf((float)deg, 1.0f);
    size_t row = (size_t)d * KT;
#pragma unroll
    for (int q = 0; q < 32; ++q) Th[row + q * HID + t] = f2bf(T[q] * dinv);
    Th[row + 5120 + t] = f2bf(x[d * HID + t]);      // root term (unscaled)
    Th[row + 5280 + t] = f2bf(sumx * dinv);         // b2 term
    oacc[d * HID + t] = 0.f;                        // zero accumulator for gemm
}

// ---- out_acc += T[2048,5440] @ Wt^T  (LDS-free, barrier-free MFMA stream) ----
// grid (16 m-blocks, 17 k-splits); block 256 = 4 waves, wave = 32m x 160n
__global__ __launch_bounds__(256) void k_gemm(const ushort* __restrict__ Th,
                                              const ushort* __restrict__ Wt,
                                              float* __restrict__ oacc) {
    int bm = blockIdx.x * 128;
    int s = blockIdx.y;
    int w = threadIdx.x >> 6, lane = threadIdx.x & 63;
    int lr = lane & 15, lk = lane >> 4;
    f32x4 acc[2][10];
#pragma unroll
    for (int mt = 0; mt < 2; ++mt)
#pragma unroll
        for (int nt = 0; nt < 10; ++nt) acc[mt][nt] = (f32x4){0.f, 0.f, 0.f, 0.f};
    const ushort* arow = Th + (size_t)(bm + w * 32 + lr) * KT;
    const ushort* brow = Wt + (size_t)lr * KT;
    for (int it = 0; it < 10; ++it) {
        int kc = (s * 10 + it) * 32 + lk * 8;
        short8 a0 = *(const short8*)&arow[kc];
        short8 a1 = *(const short8*)&arow[(size_t)16 * KT + kc];
#pragma unroll
        for (int nt = 0; nt < 10; ++nt) {
            short8 b = *(const short8*)&brow[(size_t)nt * 16 * KT + kc];
            acc[0][nt] = MFMA(a0, b, acc[0][nt]);
            acc[1][nt] = MFMA(a1, b, acc[1][nt]);
        }
    }
#pragma unroll
    for (int mt = 0; mt < 2; ++mt)
#pragma unroll
        for (int nt = 0; nt < 10; ++nt) {
            int col = nt * 16 + lr;
#pragma unroll
            for (int r = 0; r < 4; ++r) {
                int rowi = bm + w * 32 + mt * 16 + lk * 4 + r;
                atomicAdd(&oacc[rowi * HID + col], acc[mt][nt][r]);
            }
        }
}

// ---- epilogue: + bias, optional relu; writes fp32 next-x or final out ----
__global__ void k_final(const float* __restrict__ oacc, const float* __restrict__ bias,
                        float* __restrict__ xout, int relu) {
    int idx = blockIdx.x * 256 + threadIdx.x;
    int o = idx % HID;
    float v = oacc[idx] + bias[o];
    xout[idx] = relu ? fmaxf(v, 0.f) : v;
}

extern "C" void kernel_launch(void* const* d_in, const int* in_sizes, int n_in,
                              void* d_out, int out_size, void* d_ws, size_t ws_size,
                              hipStream_t stream) {
    const float* x     = (const float*)d_in[0];
    const float* ea    = (const float*)d_in[1];
    const float* w1a   = (const float*)d_in[2];
    const float* b1a   = (const float*)d_in[3];
    const float* w2a   = (const float*)d_in[4];
    const float* b2a   = (const float*)d_in[5];
    const float* roota = (const float*)d_in[6];
    const float* biasa = (const float*)d_in[7];
    const float* w1b   = (const float*)d_in[8];
    const float* b1b   = (const float*)d_in[9];
    const float* w2b   = (const float*)d_in[10];
    const float* b2b   = (const float*)d_in[11];
    const float* rootb = (const float*)d_in[12];
    const float* biasb = (const float*)d_in[13];
    const int*   ei    = (const int*)d_in[14];
    float* out = (float*)d_out;

    char* p = (char*)d_ws;
    ushort* Th = (ushort*)p;   p += (size_t)NN * KT * 2;      // 22.3 MB
    ushort* WtA = (ushort*)p;  p += (size_t)HID * KT * 2;     // 1.74 MB
    ushort* WtB = (ushort*)p;  p += (size_t)HID * KT * 2;
    float* oacc = (float*)p;   p += (size_t)NN * HID * 4;
    float* h_a = (float*)p;    p += (size_t)NE * EH * 4;
    float* h_b = (float*)p;    p += (size_t)NE * EH * 4;
    float* x1 = (float*)p;     p += (size_t)NN * HID * 4;
    float* x2 = (float*)p;     p += (size_t)NN * HID * 4;
    int* doff = (int*)p;       p += NN * 4;
    int* degg = (int*)p;       p += NN * 4;
    int* delist = (int*)p;     p += NE * 4;

    // prep (3 launches)
    k_h2<<<dim3((NE * EH) / 256, 2), 256, 0, stream>>>(ea, w1a, b1a, w1b, b1b, h_a, h_b);
    k_prepW<<<dim3(170, 2), 160, 0, stream>>>(w2a, b2a, roota, w2b, b2b, rootb, WtA, WtB);
    k_csr<<<1, 1024, 0, stream>>>(ei, doff, degg, delist);

    struct Layer { const float *xin, *h, *bias; const ushort* wt; float* xout; int relu; };
    Layer L[3] = {
        {x,  h_a, biasa, WtA, x1, 1},
        {x1, h_b, biasb, WtB, x2, 1},
        {x2, h_b, biasb, WtB, out, 0},
    };
    for (int l = 0; l < 3; ++l) {
        k_build<<<NN, 160, 0, stream>>>(L[l].xin, L[l].h, ei, doff, degg, delist,
                                        Th, oacc);
        k_gemm<<<dim3(16, 17), 256, 0, stream>>>(Th, L[l].wt, oacc);
        k_final<<<(NN * HID) / 256, 256, 0, stream>>>(oacc, L[l].bias, L[l].xout,
                                                      L[l].relu);
    }
}

// Round 7
// 196.780 us; speedup vs baseline: 1.3653x; 1.3653x over previous
//
#include <hip/hip_runtime.h>

#define NN 2048
#define NE 8192
#define ED 10
#define EH 32
#define HID 160
#define NCOL 5504   // 32*160 (w2) + 160 (b2) + 160 (root) + 64 zero-pad

typedef __attribute__((ext_vector_type(8))) short short8;
typedef __attribute__((ext_vector_type(4))) float f32x4;
typedef unsigned int u32;

__device__ __forceinline__ ushort f2bf(float v) {   // RNE
    u32 u = __float_as_uint(v);
    u += 0x7FFF + ((u >> 16) & 1);
    return (ushort)(u >> 16);
}
__device__ __forceinline__ float bf2f(ushort u) {
    return __uint_as_float(((u32)u) << 16);
}
__device__ __forceinline__ void gl2lds16(const ushort* g, ushort* l) {
    __builtin_amdgcn_global_load_lds(
        (const __attribute__((address_space(1))) u32*)g,
        (__attribute__((address_space(3))) u32*)l, 16, 0, 0);
}

// ================= single prep dispatch: all input-derived work =================
// blocks [0,512): edge MLP (2 sets); [512,856): Bt transpose (2x172 panels);
// [856,1176): x->bf16; 1176: CSR build (single block)
__global__ __launch_bounds__(256) void k_prep(
        const float* __restrict__ x, ushort* __restrict__ xb,
        const float* __restrict__ ea,
        const float* __restrict__ w1a, const float* __restrict__ b1a,
        const float* __restrict__ w1b, const float* __restrict__ b1b,
        float* __restrict__ ha, float* __restrict__ hb,
        const float* __restrict__ w2a, const float* __restrict__ b2a,
        const float* __restrict__ roota,
        const float* __restrict__ w2b, const float* __restrict__ b2b,
        const float* __restrict__ rootb,
        ushort* __restrict__ BtA, ushort* __restrict__ BtB,
        const int* __restrict__ ei, int* __restrict__ doff,
        int* __restrict__ degg, float* __restrict__ dinv,
        int* __restrict__ delist) {
    __shared__ char smem[20608];
    int b = blockIdx.x, t = threadIdx.x;

    if (b < 512) {                       // ---- h = relu(ea@w1+b1), 4 elems/thread
        int set = b >> 8, rel = b & 255;
        const float* w1 = set ? w1b : w1a;
        const float* b1 = set ? b1b : b1a;
        float* h = set ? hb : ha;
        int idx = rel * 1024 + t * 4;
        int e = idx >> 5, j0 = idx & 31;
        float o4[4];
#pragma unroll
        for (int u = 0; u < 4; ++u) {
            float acc = b1[j0 + u];
#pragma unroll
            for (int i = 0; i < ED; ++i) acc += ea[e * ED + i] * w1[i * EH + j0 + u];
            o4[u] = fmaxf(acc, 0.f);
        }
        *(float4*)&h[idx] = *(const float4*)o4;
        return;
    }
    if (b < 856) {                       // ---- Bt[n][k] bf16 via LDS transpose
        int rel = b - 512;
        int set = rel / 172, pb = rel - set * 172;
        float (*tile)[161] = (float(*)[161])smem;
        const float* w2 = set ? w2b : w2a;
        const float* b2 = set ? b2b : b2a;
        const float* root = set ? rootb : roota;
        ushort* Bt = set ? BtB : BtA;
        const float* src;
        int n0, zero = 0;
        if (pb < 160)      { int q = pb / 5, op = pb - q * 5; n0 = q * 160 + op * 32; src = w2 + q * 25600 + op * 32; }
        else if (pb < 165) { int ip = pb - 160; n0 = 5120 + ip * 32; src = b2 + ip * 32; }
        else if (pb < 170) { int ip = pb - 165; n0 = 5280 + ip * 32; src = root + ip * 32; }
        else               { n0 = 5440 + (pb - 170) * 32; src = b2; zero = 1; }
        int kl = t >> 5, ol = t & 31;
#pragma unroll
        for (int pass = 0; pass < 20; ++pass) {
            int k = pass * 8 + kl;
            tile[ol][k] = zero ? 0.f : src[k * HID + ol];
        }
        __syncthreads();
        int on = t >> 3, j = t & 7;
        int n = n0 + on;
#pragma unroll
        for (int i = 0; i < 20; i += 2) {
            int k = j * 20 + i;
            u32 pk = ((u32)f2bf(tile[on][k + 1]) << 16) | f2bf(tile[on][k]);
            *(u32*)&Bt[(size_t)n * HID + k] = pk;
        }
        return;
    }
    if (b < 1176) {                      // ---- x -> bf16, 4 elems/thread
        int idx = (b - 856) * 1024 + t * 4;
        float4 xv = *(const float4*)&x[idx];
        ushort o4[4] = {f2bf(xv.x), f2bf(xv.y), f2bf(xv.z), f2bf(xv.w)};
        *(u32*)&xb[idx] = *(const u32*)&o4[0];
        *(u32*)&xb[idx + 2] = *(const u32*)&o4[2];
        return;
    }
    // ---- CSR build over dst (single block, 256 threads)
    int* deg = (int*)smem;               // NN
    int* cur = deg + NN;                 // NN
    int* part = cur + NN;                // 256
    for (int i = t; i < NN; i += 256) deg[i] = 0;
    __syncthreads();
    for (int e = t; e < NE; e += 256) atomicAdd(&deg[ei[NE + e]], 1);
    __syncthreads();
    int loc[8], s = 0;
#pragma unroll
    for (int i = 0; i < 8; ++i) { loc[i] = s; s += deg[t * 8 + i]; }
    part[t] = s;
    __syncthreads();
    int tot = s;
    for (int st = 1; st < 256; st <<= 1) {
        int v = (t >= st) ? part[t - st] : 0;
        __syncthreads();
        part[t] += v;
        __syncthreads();
    }
    int base = part[t] - tot;
#pragma unroll
    for (int i = 0; i < 8; ++i) {
        int d = t * 8 + i;
        doff[d] = base + loc[i];
        cur[d] = base + loc[i];
        degg[d] = deg[d];
        dinv[d] = 1.0f / fmaxf((float)deg[d], 1.0f);
    }
    __syncthreads();
    for (int e = t; e < NE; e += 256) {
        int d = ei[NE + e];
        int p = atomicAdd(&cur[d], 1);
        delist[p] = e;
    }
}

// ======== G[2048,5504] bf16 = xb[2048,160] @ Bt^T, single-bf16 MFMA ========
__global__ __launch_bounds__(256) void k_gemm(const ushort* __restrict__ A,
                                              const ushort* __restrict__ B,
                                              ushort* __restrict__ G) {
    __shared__ ushort sA[128 * 32], sB[128 * 32];
    int tid = threadIdx.x;
    int bn = blockIdx.x * 128, bm = blockIdx.y * 128;
    int wid = tid >> 6, lane = tid & 63;
    int wm = (wid >> 1) * 64, wn = (wid & 1) * 64;
    int lr = lane & 15, lk = lane >> 4;
    f32x4 acc[4][4];
#pragma unroll
    for (int i = 0; i < 4; ++i)
#pragma unroll
        for (int j = 0; j < 4; ++j) acc[i][j] = (f32x4){0.f, 0.f, 0.f, 0.f};

    for (int c = 0; c < 5; ++c) {
        int k0 = c * 32;
#pragma unroll
        for (int i = 0; i < 2; ++i) {
            int s = tid + i * 256;
            int r = s >> 2, go = (s & 3) * 8;
            gl2lds16(&A[(size_t)(bm + r) * HID + k0 + go], &sA[s * 8]);
            gl2lds16(&B[(size_t)(bn + r) * HID + k0 + go], &sB[s * 8]);
        }
        __syncthreads();
        short8 av[4];
#pragma unroll
        for (int mt = 0; mt < 4; ++mt)
            av[mt] = *(const short8*)&sA[(wm + mt * 16 + lr) * 32 + lk * 8];
#pragma unroll
        for (int nt = 0; nt < 4; ++nt) {
            short8 bv = *(const short8*)&sB[(wn + nt * 16 + lr) * 32 + lk * 8];
#pragma unroll
            for (int mt = 0; mt < 4; ++mt)
                acc[mt][nt] = __builtin_amdgcn_mfma_f32_16x16x32_bf16(av[mt], bv, acc[mt][nt], 0, 0, 0);
        }
        __syncthreads();
    }
#pragma unroll
    for (int mt = 0; mt < 4; ++mt)
#pragma unroll
        for (int nt = 0; nt < 4; ++nt) {
            int m0 = bm + wm + mt * 16 + lk * 4;
            int n = bn + wn + nt * 16 + lr;
#pragma unroll
            for (int r = 0; r < 4; ++r)
                G[(size_t)(m0 + r) * NCOL + n] = f2bf(acc[mt][nt][r]);
        }
}

// ==== dst-grouped aggregation fused with epilogue (mean+root+bias+relu+cvt) ====
__global__ __launch_bounds__(160) void k_aggr(const ushort* __restrict__ G,
        const float* __restrict__ h, const int* __restrict__ ei,
        const int* __restrict__ doff, const int* __restrict__ degg,
        const float* __restrict__ dinv, const int* __restrict__ delist,
        const float* __restrict__ bias, ushort* __restrict__ xn,
        float* __restrict__ out, int last) {
    __shared__ float hbuf[16 * EH];
    __shared__ int ebuf[16], sbuf[16];
    int d = blockIdx.x, t = threadIdx.x;
    int o0 = doff[d], dg = degg[d];
    float acc = 0.f;
    for (int c0 = 0; c0 < dg; c0 += 16) {
        int nc = min(16, dg - c0);
        if (t < nc) {
            int e = delist[o0 + c0 + t];
            ebuf[t] = e;
            sbuf[t] = ei[e];               // src
        }
        __syncthreads();
        for (int i = t; i < nc * EH; i += 160)
            hbuf[i] = h[ebuf[i >> 5] * EH + (i & 31)];
        __syncthreads();
        for (int j = 0; j < nc; ++j) {
            const ushort* Gr = G + (size_t)sbuf[j] * NCOL;
            const float* hj = &hbuf[j * EH];
            float a = bf2f(Gr[5120 + t]);  // b2 (xb) term
#pragma unroll
            for (int q = 0; q < 32; ++q)
                a += hj[q] * bf2f(Gr[q * HID + t]);
            acc += a;
        }
        __syncthreads();
    }
    float v = acc * dinv[d] + bf2f(G[(size_t)d * NCOL + 5280 + t]) + bias[t];
    if (last) out[d * HID + t] = v;
    else      xn[d * HID + t] = f2bf(fmaxf(v, 0.f));
}

extern "C" void kernel_launch(void* const* d_in, const int* in_sizes, int n_in,
                              void* d_out, int out_size, void* d_ws, size_t ws_size,
                              hipStream_t stream) {
    const float* x     = (const float*)d_in[0];
    const float* ea    = (const float*)d_in[1];
    const float* w1a   = (const float*)d_in[2];
    const float* b1a   = (const float*)d_in[3];
    const float* w2a   = (const float*)d_in[4];
    const float* b2a   = (const float*)d_in[5];
    const float* roota = (const float*)d_in[6];
    const float* biasa = (const float*)d_in[7];
    const float* w1b   = (const float*)d_in[8];
    const float* b1b   = (const float*)d_in[9];
    const float* w2b   = (const float*)d_in[10];
    const float* b2b   = (const float*)d_in[11];
    const float* rootb = (const float*)d_in[12];
    const float* biasb = (const float*)d_in[13];
    const int*   ei    = (const int*)d_in[14];
    float* out = (float*)d_out;

    char* p = (char*)d_ws;
    ushort* G = (ushort*)p;    p += (size_t)NN * NCOL * 2;    // 22.5 MB
    ushort* BtA = (ushort*)p;  p += (size_t)NCOL * HID * 2;
    ushort* BtB = (ushort*)p;  p += (size_t)NCOL * HID * 2;
    float* h_a = (float*)p;    p += (size_t)NE * EH * 4;
    float* h_b = (float*)p;    p += (size_t)NE * EH * 4;
    ushort* xb0 = (ushort*)p;  p += (size_t)NN * HID * 2;
    ushort* xn = (ushort*)p;   p += (size_t)NN * HID * 2;
    int* doff = (int*)p;       p += NN * 4;
    int* degg = (int*)p;       p += NN * 4;
    float* dinv = (float*)p;   p += NN * 4;
    int* delist = (int*)p;     p += NE * 4;

    k_prep<<<1177, 256, 0, stream>>>(x, xb0, ea, w1a, b1a, w1b, b1b, h_a, h_b,
                                     w2a, b2a, roota, w2b, b2b, rootb, BtA, BtB,
                                     ei, doff, degg, dinv, delist);

    struct Layer { const ushort *xin, *bt; const float *h, *bias; int last; };
    Layer L[3] = {
        {xb0, BtA, h_a, biasa, 0},
        {xn,  BtB, h_b, biasb, 0},
        {xn,  BtB, h_b, biasb, 1},
    };
    for (int l = 0; l < 3; ++l) {
        k_gemm<<<dim3(NCOL / 128, NN / 128), 256, 0, stream>>>(L[l].xin, L[l].bt, G);
        k_aggr<<<NN, 160, 0, stream>>>(G, L[l].h, ei, doff, degg, dinv, delist,
                                       L[l].bias, xn, out, L[l].last);
    }
}